// Round 14
// baseline (27989.505 us; speedup 1.0000x reference)
//
#include <hip/hip_runtime.h>
#include <hip/hip_fp16.h>
#include <stdint.h>

// ---------------- problem constants ----------------
#define T_STEPS 1000
#define G4      1024
#define NOUT    100
#define NW      20
#define NTHM    1024    // 16 waves
#define NGROUPS 8       // batch groups of 16 rows
#define BT      16
#define HLAG    5       // head lag (amortizes the 3-hop feedback cycle)
#define NSLOT   8       // hbuf ring slots

// ---------------- ws layout (dword offsets) ----------------
// hbuf: [8 groups][3 layers][8 slots][16 rows][128 dw]
constexpr int    OFF_HBUF  = 0;
constexpr int    HBUF_DW   = NGROUPS*3*NSLOT*16*128;         // 393216 (1.5 MB)
constexpr int    OFF_CNT   = HBUF_DW;                        // [8][48]: cnt_L at g*48 + L*16
constexpr int    OFF_HEADW = OFF_CNT + NGROUPS*48;           // [120][132] fp16-pair dw
constexpr int    OFF_HXB   = OFF_HEADW + 120*132;            // [120][3] f32
constexpr int    OFF_MISC  = OFF_HXB + 360;                  // [3 roles][3][1024] f32
constexpr int    OFF_WREG  = OFF_MISC + 3*3*1024;            // [3 roles][64 slots][1024 thr][4dw]
constexpr size_t WS_DW     = (size_t)OFF_WREG + (size_t)3*64*1024*4;  // ~4.82 MB
constexpr size_t GOFF      = (size_t)128*1000*100;

__device__ __forceinline__ float sigf(float x)     { return 1.0f / (1.0f + __expf(-x)); }
__device__ __forceinline__ float tanhfast(float x) { return 2.0f / (1.0f + __expf(-2.0f * x)) - 1.0f; }

typedef _Float16 h2v    __attribute__((ext_vector_type(2)));
typedef _Float16 f16x8v __attribute__((ext_vector_type(8)));
typedef float    f32x4v __attribute__((ext_vector_type(4)));
#define MFMA16(A, B, C) __builtin_amdgcn_mfma_f32_16x16x32_f16((A), (B), (C), 0, 0, 0)

__device__ __forceinline__ float dot2f(uint32_t w, uint32_t h, float acc) {
    return __builtin_amdgcn_fdot2(__builtin_bit_cast(h2v, w),
                                  __builtin_bit_cast(h2v, h), acc, false);
}
__device__ __forceinline__ uint32_t pk(float a, float b) {
    __half2 h = __floats2half2_rn(a, b);
    return *reinterpret_cast<uint32_t*>(&h);
}
#define F4E(v, u) ((u) == 0 ? (v).x : (u) == 1 ? (v).y : (u) == 2 ? (v).z : (v).w)

// Weight B-fragment dword for (role rw, thread tid, slot, dword d).
// 16 waves x 4 ntl = 64 ntiles of 16 gate cols. nt = wave*4+ntl.
// j = (nt>>4)*256 + (nt&15)*16 + (lane&15); k = kt*32 + (lane>>4)*8 + 2d.
// rw0: slot = ntl*8+kt (kt<8, Whh0). rw1/2: slot = ntl*16+kt; kt<8 skip Wih, kt>=8 recur Whh.
__device__ __forceinline__ uint32_t fetch_wdw(int rw, int tid, int slot, int d,
                                              const float* __restrict__ Whh0,
                                              const float* __restrict__ WihL,
                                              const float* __restrict__ WhhL) {
    int wave = tid >> 6, lane = tid & 63;
    int khalf = lane >> 4;
    int ntl, kt;
    if (rw == 0) { ntl = slot >> 3; kt = slot & 7; }
    else         { ntl = slot >> 4; kt = slot & 15; }
    int nt = wave*4 + ntl;
    int j = (nt >> 4)*256 + (nt & 15)*16 + (lane & 15);
    if (rw == 0) {
        int k = kt*32 + khalf*8 + 2*d;
        return pk(Whh0[(size_t)j*256 + k], Whh0[(size_t)j*256 + k + 1]);
    }
    if (kt < 8) {
        int k = kt*32 + khalf*8 + 2*d;
        const float* Wi = WihL + (size_t)(rw-1)*G4*258;
        return pk(Wi[(size_t)j*258 + 2 + k], Wi[(size_t)j*258 + 3 + k]);
    }
    int k = (kt-8)*32 + khalf*8 + 2*d;
    const float* Wh = WhhL + (size_t)(rw-1)*G4*256;
    return pk(Wh[(size_t)j*256 + k], Wh[(size_t)j*256 + k + 1]);
}

// ---------------- prep kernels ----------------
__global__ void pack_wreg(const float* __restrict__ Whh0, const float* __restrict__ WihL,
                          const float* __restrict__ WhhL, uint32_t* __restrict__ wsd) {
    int slot = blockIdx.x & 63, rw = blockIdx.x >> 6;   // grid 3*64, 1024 thr
    if (rw == 0 && slot >= 32) return;
    int tid = threadIdx.x;
    uint32_t* dst = wsd + OFF_WREG + ((size_t)(rw*64 + slot)*1024 + tid)*4;
    dst[0] = fetch_wdw(rw, tid, slot, 0, Whh0, WihL, WhhL);
    dst[1] = fetch_wdw(rw, tid, slot, 1, Whh0, WihL, WhhL);
    dst[2] = fetch_wdw(rw, tid, slot, 2, Whh0, WihL, WhhL);
    dst[3] = fetch_wdw(rw, tid, slot, 3, Whh0, WihL, WhhL);
}

__global__ void pack_misc(const float* __restrict__ Wih0,
                          const float* __restrict__ bih0, const float* __restrict__ bhh0,
                          const float* __restrict__ WihL,
                          const float* __restrict__ bihL, const float* __restrict__ bhhL,
                          uint32_t* __restrict__ wsd) {
    int id = blockIdx.x * blockDim.x + threadIdx.x;
    if (id >= 3*3*1024) return;
    int rw = id / 3072, rem = id % 3072;
    int qq = rem / 1024, j = rem % 1024;
    float v;
    if (rw == 0)      v = (qq == 0) ? bih0[j] + bhh0[j] : Wih0[j*2 + (qq-1)];
    else if (rw == 1) v = (qq == 0) ? bihL[j] + bhhL[j] : WihL[(size_t)j*258 + (qq-1)];
    else              v = (qq == 0) ? bihL[G4+j] + bhhL[G4+j]
                                    : WihL[(size_t)G4*258 + (size_t)j*258 + (qq-1)];
    ((float*)wsd)[OFF_MISC + id] = v;
}

__global__ void pack_head(const float* __restrict__ Wg, const float* __restrict__ bg,
                          const float* __restrict__ Ww, const float* __restrict__ bw,
                          uint32_t* __restrict__ wsd) {
    int id = blockIdx.x * blockDim.x + threadIdx.x;
    if (id < 120*132) {
        int jo = id / 132, d = id % 132;
        uint32_t v = 0;
        if (d < 128) {
            int k = 2*d;
            const float* row = (jo < 100) ? (Wg + (size_t)jo*258) : (Ww + (size_t)(jo-100)*258);
            v = pk(row[2+k], row[3+k]);
        }
        wsd[OFF_HEADW + id] = v;
    } else if (id < 120*132 + 360) {
        int p = id - 120*132, jo = p/3, qq = p%3;
        const float* row = (jo < 100) ? (Wg + (size_t)jo*258) : (Ww + (size_t)(jo-100)*258);
        float v = (qq == 0) ? ((jo < 100) ? bg[jo] : bw[jo-100]) : row[qq-1];
        ((float*)wsd)[OFF_HXB + p] = v;
    }
}

__global__ void zero_cnt(uint32_t* __restrict__ wsd) {
    int id = blockIdx.x * blockDim.x + threadIdx.x;
    if (id < NGROUPS*48) wsd[OFF_CNT + id] = 0;
}

// ---------------- sync (r11-proven counter protocol, 1 producer/counter) ----------------
// Ring-8 + spread bound: role1<=role0, role2<=role1 (data), role0<=role2+HLAG+1 (head)
// -> spread <= 6 < 8 slots. Overwrite safety verified slot-by-slot per layer.
__device__ __forceinline__ void pollCnt(uint32_t* c, uint32_t tgt) {
    int spins = 0;
    while (__hip_atomic_load(c, __ATOMIC_RELAXED, __HIP_MEMORY_SCOPE_AGENT) < tgt) {
        __builtin_amdgcn_s_sleep(1);
        if (++spins > (1 << 24)) break;   // bailout: loud wrong answer beats a hang
    }
}
__device__ __forceinline__ void postCnt(uint32_t* c, uint32_t val) {
    __hip_atomic_store(c, val, __ATOMIC_RELAXED, __HIP_MEMORY_SCOPE_AGENT);
}

// read 16x128 dw of layer L slot S into h_in (one u64/thread, coalesced)
#define READH(L, SLOT)                                                             \
    { int r_ = tid >> 6, q_ = tid & 63;                                            \
      uint64_t v_ = __hip_atomic_load(hbuf64 + ((size_t)((L)*NSLOT + (SLOT))*16 + r_)*64 + q_, \
                                      __ATOMIC_RELAXED, __HIP_MEMORY_SCOPE_AGENT); \
      *(uint64_t*)&h_in[r_][2*q_] = v_; }

#define DWRITE()                                                                   \
    { _Pragma("unroll")                                                            \
      for (int ntl = 0; ntl < 4; ++ntl) {                                          \
          int col_ = (wave*4 + ntl)*16 + rA;                                       \
          _Pragma("unroll")                                                        \
          for (int rg = 0; rg < 4; ++rg)                                           \
              g_s[(m0 + rg)*1028 + col_] = ac[ntl][rg];                            \
      } }

// thread (r_=tid>>6, q_=tid&63) handles units 4q_..4q_+3 of row r_
#define UPDATE_STORE(LYR, SLOT)                                                    \
    { int r_ = tid >> 6, q_ = tid & 63;                                            \
      float x0 = x_cur[par][r_][0], x1 = x_cur[par][r_][1];                        \
      float4 gq[4], bq[4], w0q[4], w1q[4];                                         \
      _Pragma("unroll")                                                            \
      for (int gg = 0; gg < 4; ++gg) {                                             \
          gq[gg]  = *(const float4*)&g_s[r_*1028 + gg*256 + 4*q_];                 \
          bq[gg]  = *(const float4*)&misc_s[0*1024 + gg*256 + 4*q_];               \
          w0q[gg] = *(const float4*)&misc_s[1*1024 + gg*256 + 4*q_];               \
          w1q[gg] = *(const float4*)&misc_s[2*1024 + gg*256 + 4*q_];               \
      }                                                                            \
      float hv4[4];                                                                \
      _Pragma("unroll")                                                            \
      for (int u = 0; u < 4; ++u) {                                                \
          float gi = F4E(gq[0],u) + F4E(bq[0],u) + x0*F4E(w0q[0],u) + x1*F4E(w1q[0],u); \
          float gf = F4E(gq[1],u) + F4E(bq[1],u) + x0*F4E(w0q[1],u) + x1*F4E(w1q[1],u); \
          float gg_ = F4E(gq[2],u) + F4E(bq[2],u) + x0*F4E(w0q[2],u) + x1*F4E(w1q[2],u); \
          float go = F4E(gq[3],u) + F4E(bq[3],u) + x0*F4E(w0q[3],u) + x1*F4E(w1q[3],u); \
          float cc = sigf(gf)*c4[u] + sigf(gi)*tanhfast(gg_);                      \
          hv4[u] = sigf(go)*tanhfast(cc);  c4[u] = cc;                             \
      }                                                                            \
      uint32_t plo = pk(hv4[0], hv4[1]), phi = pk(hv4[2], hv4[3]);                 \
      uint2 pv; pv.x = plo; pv.y = phi;                                            \
      *(uint2*)&h_own[r_][2*q_] = pv;                                              \
      uint64_t p64 = (uint64_t)plo | ((uint64_t)phi << 32);                        \
      __hip_atomic_store(hbuf64 + ((size_t)((LYR)*NSLOT + (SLOT))*16 + r_)*64 + q_, \
                         p64, __ATOMIC_RELAXED, __HIP_MEMORY_SCOPE_AGENT);         \
    }

template <bool WSPACK>
__global__ __launch_bounds__(NTHM, 1)
void lstm_pipe(const float* __restrict__ x, uint32_t* __restrict__ wsd,
               float* __restrict__ out,
               const float* __restrict__ Whh0, const float* __restrict__ WihL,
               const float* __restrict__ WhhL) {
    __shared__ __align__(16) uint32_t headw_s[120*132];    // 63360 B
    __shared__ __align__(16) float    g_s[16*1028];        // 65792 B (padded rows)
    __shared__ __align__(16) uint32_t h_own[16][132];      // own-layer h (fp16 pairs)
    __shared__ __align__(16) uint32_t h_in[16][132];       // skip / head input
    __shared__ float    misc_s[3*1024];
    __shared__ float    x_cur[2][16][2];
    __shared__ float    x_ring[NSLOT][16][2];
    __shared__ float    wl_s[16][NW];
    __shared__ float    hxb_s[360];

    const int tid = threadIdx.x;
    const int bid = blockIdx.x;
    const int g  = bid & 7;       // roles of a group at bids g, 8+g, 16+g -> same XCD
    const int rw = bid >> 3;      // 0 = L0+head, 1 = L1, 2 = L2
    const int b0 = g * BT;
    const int wave = tid >> 6, lane = tid & 63;
    const int rA = lane & 15, khalf = lane >> 4;
    const int m0 = khalf * 4;

    uint64_t* hbuf64 = (uint64_t*)(wsd + OFF_HBUF) + (size_t)g * 3 * NSLOT * 1024;
    uint32_t* cnt = wsd + OFF_CNT + g * 48;
    const float* wsf = (const float*)wsd;

    // ---- persistent full-layer weights: B-fragments across VGPR+AGPR ----
    f16x8v wrf[64];
    const int nslot = (rw == 0) ? 32 : 64;
    if (WSPACK) {
#pragma unroll
        for (int s = 0; s < 64; ++s) {
            if (s < nslot) {
                uint4 v = *(const uint4*)(wsd + OFF_WREG + ((size_t)(rw*64 + s)*1024 + tid)*4);
                wrf[s] = __builtin_bit_cast(f16x8v, v);
            } else {
                uint4 z = {0,0,0,0};
                wrf[s] = __builtin_bit_cast(f16x8v, z);
            }
        }
    } else {
#pragma unroll
        for (int s = 0; s < 64; ++s) {
            uint4 v = {0,0,0,0};
            if (s < nslot) {
                v.x = fetch_wdw(rw, tid, s, 0, Whh0, WihL, WhhL);
                v.y = fetch_wdw(rw, tid, s, 1, Whh0, WihL, WhhL);
                v.z = fetch_wdw(rw, tid, s, 2, Whh0, WihL, WhhL);
                v.w = fetch_wdw(rw, tid, s, 3, Whh0, WihL, WhhL);
            }
            wrf[s] = __builtin_bit_cast(f16x8v, v);
        }
    }

    // ---- init LDS ----
    for (int i = tid; i < 16*132; i += NTHM) { (&h_own[0][0])[i] = 0u; (&h_in[0][0])[i] = 0u; }
    for (int i = tid; i < 3072;   i += NTHM) misc_s[i] = wsf[OFF_MISC + rw*3072 + i];
    if (rw == 0) {
        for (int i = tid; i < 120*132; i += NTHM) headw_s[i] = wsd[OFF_HEADW + i];
        for (int i = tid; i < 360;     i += NTHM) hxb_s[i]   = wsf[OFF_HXB + i];
    }
    float c4[4] = {0.0f, 0.0f, 0.0f, 0.0f};
    __syncthreads();

    const f32x4v zf4 = {0.0f, 0.0f, 0.0f, 0.0f};

    if (rw == 0) {
        // ========== role0: L0 (recurrence fully LDS-local) + head (lag 5) ==========
        for (int t = 0; t <= T_STEPS - 1 + HLAG; ++t) {
            const bool doL0 = (t < T_STEPS);
            const bool doHd = (t >= HLAG);
            const int th = t - HLAG;
            const int par = t & 1;
            const int sl = t & (NSLOT-1), slh = th & (NSLOT-1);
            if (tid == 0 && doHd) pollCnt(cnt + 2*16, (uint32_t)(th + 1));
            __syncthreads();                                   // A
            if (doHd) READH(2, slh)
            if (doL0 && tid < 32) {
                float xv = x[((size_t)(b0 + (tid >> 1))*T_STEPS + t)*2 + (tid & 1)];
                x_cur[par][tid >> 1][tid & 1] = xv;
                x_ring[sl][tid >> 1][tid & 1] = xv;
            }
            __syncthreads();                                   // B
            if (doL0) {
                f32x4v ac[4] = {zf4, zf4, zf4, zf4};
#pragma unroll
                for (int kt = 0; kt < 8; ++kt) {
                    uint4 hv = *(const uint4*)&h_own[rA][kt*16 + khalf*4];
                    f16x8v a = __builtin_bit_cast(f16x8v, hv);
#pragma unroll
                    for (int ntl = 0; ntl < 4; ++ntl)
                        ac[ntl] = MFMA16(a, wrf[ntl*8 + kt], ac[ntl]);
                }
                DWRITE()
            }
            __syncthreads();                                   // C
            if (doL0) UPDATE_STORE(0, sl)
            __syncthreads();                                   // D
            if (tid == 0 && doL0) postCnt(cnt + 0, (uint32_t)(t + 1));
            if (doHd) {
                int jo8 = tid >> 3, kh = tid & 7;
                for (int r = 0; r < 16; ++r) {
                    float a = 0.0f;
                    if (jo8 < 120) {
#pragma unroll
                        for (int d4 = 0; d4 < 4; ++d4) {
                            uint4 wv = *(const uint4*)&headw_s[jo8*132 + kh*16 + d4*4];
                            uint4 hv = *(const uint4*)&h_in[r][kh*16 + d4*4];
                            a = dot2f(wv.x, hv.x, a); a = dot2f(wv.y, hv.y, a);
                            a = dot2f(wv.z, hv.z, a); a = dot2f(wv.w, hv.w, a);
                        }
                    }
                    a += __shfl_xor(a, 1); a += __shfl_xor(a, 2); a += __shfl_xor(a, 4);
                    if (kh == 0 && jo8 < 120) {
                        float xa = x_ring[slh][r][0], xb = x_ring[slh][r][1];
                        a += hxb_s[jo8*3] + xa*hxb_s[jo8*3+1] + xb*hxb_s[jo8*3+2];
                        if (jo8 < NOUT) out[((size_t)(b0 + r)*T_STEPS + th)*NOUT + jo8] = a;
                        else            wl_s[r][jo8 - NOUT] = a;
                    }
                }
                __syncthreads();
                if (tid < 16) {
                    int r = tid;
                    float mx = -1e30f;
#pragma unroll
                    for (int m = 0; m < NW; ++m) mx = fmaxf(mx, wl_s[r][m]);
                    float ss = 0.0f, ee[NW];
#pragma unroll
                    for (int m = 0; m < NW; ++m) { ee[m] = __expf(wl_s[r][m] - mx); ss += ee[m]; }
                    float inv = 1.0f / ss;
                    size_t bo = GOFF + ((size_t)(b0 + r)*T_STEPS + th)*NW;
#pragma unroll
                    for (int m = 0; m < NW; ++m) out[bo + m] = ee[m]*inv;
                }
            }
        }
    } else {
        // ========== role1/2: skip (cross-WG, aged) + recur (LDS-local) ==========
        const int IN_L = rw - 1, OWN_L = rw;
        for (int t = 0; t < T_STEPS; ++t) {
            const int par = t & 1;
            const int sl = t & (NSLOT-1);
            if (tid == 0) pollCnt(cnt + IN_L*16, (uint32_t)(t + 1));
            __syncthreads();                                   // A
            READH(IN_L, sl)
            if (tid < 32) {
                float xv = x[((size_t)(b0 + (tid >> 1))*T_STEPS + t)*2 + (tid & 1)];
                x_cur[par][tid >> 1][tid & 1] = xv;
            }
            __syncthreads();                                   // B
            {
                f32x4v ac[4] = {zf4, zf4, zf4, zf4};
#pragma unroll
                for (int kt = 0; kt < 8; ++kt) {               // skip matrix (h_in)
                    uint4 hv = *(const uint4*)&h_in[rA][kt*16 + khalf*4];
                    f16x8v a = __builtin_bit_cast(f16x8v, hv);
#pragma unroll
                    for (int ntl = 0; ntl < 4; ++ntl)
                        ac[ntl] = MFMA16(a, wrf[ntl*16 + kt], ac[ntl]);
                }
#pragma unroll
                for (int kt = 0; kt < 8; ++kt) {               // recur matrix (h_own, local)
                    uint4 hv = *(const uint4*)&h_own[rA][kt*16 + khalf*4];
                    f16x8v a = __builtin_bit_cast(f16x8v, hv);
#pragma unroll
                    for (int ntl = 0; ntl < 4; ++ntl)
                        ac[ntl] = MFMA16(a, wrf[ntl*16 + 8 + kt], ac[ntl]);
                }
                DWRITE()
            }
            __syncthreads();                                   // C
            UPDATE_STORE(OWN_L, sl)
            __syncthreads();                                   // D
            if (tid == 0) postCnt(cnt + OWN_L*16, (uint32_t)(t + 1));
        }
    }
}

extern "C" void kernel_launch(void* const* d_in, const int* in_sizes, int n_in,
                              void* d_out, int out_size, void* d_ws, size_t ws_size,
                              hipStream_t stream) {
    const float* x    = (const float*)d_in[0];
    const float* Wih0 = (const float*)d_in[1];
    const float* Whh0 = (const float*)d_in[2];
    const float* bih0 = (const float*)d_in[3];
    const float* bhh0 = (const float*)d_in[4];
    const float* WihL = (const float*)d_in[5];
    const float* WhhL = (const float*)d_in[6];
    const float* bihL = (const float*)d_in[7];
    const float* bhhL = (const float*)d_in[8];
    const float* Wg   = (const float*)d_in[9];
    const float* bg   = (const float*)d_in[10];
    const float* Ww   = (const float*)d_in[11];
    const float* bw   = (const float*)d_in[12];
    float*    out = (float*)d_out;
    uint32_t* wsd = (uint32_t*)d_ws;
    (void)in_sizes; (void)n_in; (void)out_size;

    const bool wspack = ws_size >= WS_DW * 4;

    zero_cnt<<<2, 256, 0, stream>>>(wsd);
    pack_misc<<<36, 256, 0, stream>>>(Wih0, bih0, bhh0, WihL, bihL, bhhL, wsd);
    pack_head<<<64, 256, 0, stream>>>(Wg, bg, Ww, bw, wsd);
    if (wspack)
        pack_wreg<<<3*64, 1024, 0, stream>>>(Whh0, WihL, WhhL, wsd);

    dim3 grid(NGROUPS * 3), block(NTHM);
    void* args[] = {(void*)&x, (void*)&wsd, (void*)&out,
                    (void*)&Whh0, (void*)&WihL, (void*)&WhhL};
    if (wspack) {
        hipError_t err = hipLaunchCooperativeKernel((const void*)lstm_pipe<true>,
                                                    grid, block, args, 0, stream);
        if (err != hipSuccess)
            lstm_pipe<true><<<grid, block, 0, stream>>>(x, wsd, out, Whh0, WihL, WhhL);
    } else {
        hipError_t err = hipLaunchCooperativeKernel((const void*)lstm_pipe<false>,
                                                    grid, block, args, 0, stream);
        if (err != hipSuccess)
            lstm_pipe<false><<<grid, block, 0, stream>>>(x, wsd, out, Whh0, WihL, WhhL);
    }
}

// Round 15
// 3958.994 us; speedup vs baseline: 7.0699x; 7.0699x over previous
//
#include <hip/hip_runtime.h>
#include <hip/hip_fp16.h>
#include <stdint.h>

// ---------------- problem constants ----------------
#define T_STEPS 1000
#define G4      1024
#define NOUT    100
#define NW      20
#define NTHM    512
#define NGROUPS 8       // batch groups of 16 rows
#define NROLE   12      // 0-3 stage0(L0+head), 4-7 stage1, 8-11 stage2; U=64 each
#define BT      16

// ---------------- ws layout (dword offsets) ----------------
// hbuf: [8 groups][3 layers][4 slots][16 rows][64 u64]
constexpr int    OFF_HBUF  = 0;
constexpr int    OFF_CNT   = OFF_HBUF + NGROUPS*3*4*16*128;  // 196608: [8][448] (only 3 PCs used)
constexpr int    OFF_HEADW = OFF_CNT + NGROUPS*448;          // 200192: [120][132]
constexpr int    OFF_HXB   = OFF_HEADW + 120*132;            // 216032: [120][3] f32
constexpr int    OFF_MISC  = OFF_HXB + 360;                  // 216392: [12 roles][3][4][64] f32
constexpr int    OFF_WREG  = OFF_MISC + NROLE*768;           // 225608: [12 roles][32 slots][512 thr][4dw]
constexpr size_t WS_DW     = (size_t)OFF_WREG + (size_t)NROLE*32*512*4;  // ~4.05 MB
constexpr size_t GOFF      = (size_t)128*1000*100;

__device__ __forceinline__ float sigf(float x)     { return 1.0f / (1.0f + __expf(-x)); }
__device__ __forceinline__ float tanhfast(float x) { return 2.0f / (1.0f + __expf(-2.0f * x)) - 1.0f; }

typedef _Float16 h2v    __attribute__((ext_vector_type(2)));
typedef _Float16 f16x8v __attribute__((ext_vector_type(8)));
typedef float    f32x4v __attribute__((ext_vector_type(4)));
#define MFMA16(A, B, C) __builtin_amdgcn_mfma_f32_16x16x32_f16((A), (B), (C), 0, 0, 0)

__device__ __forceinline__ float dot2f(uint32_t w, uint32_t h, float acc) {
    return __builtin_amdgcn_fdot2(__builtin_bit_cast(h2v, w),
                                  __builtin_bit_cast(h2v, h), acc, false);
}
__device__ __forceinline__ uint32_t pk(float a, float b) {
    __half2 h = __floats2half2_rn(a, b);
    return *reinterpret_cast<uint32_t*>(&h);
}

__device__ __forceinline__ void role_params(int rw, int& stage, int& idx, int& U, int& u0) {
    stage = rw >> 2; idx = rw & 3; U = 64; u0 = 64*idx;
}

// B-fragment weight dword (role rw, thread tid, slot = ntl*16+kt, dword d).
// wave=tid>>6, lane=tid&63; nt = 2*wave+ntl (NT=16).
// j = gate*256 + u0 + usub*16 + (lane&15); k = [kt or kt-8]*32 + (lane>>4)*8 + 2d.
// kt<8: stage0 Whh0 / stage1,2 skip Wih; kt>=8: recur Whh (stage0 unused -> 0).
__device__ __forceinline__ uint32_t fetch_wdw(int rw, int tid, int slot, int d,
                                              const float* __restrict__ Whh0,
                                              const float* __restrict__ WihL,
                                              const float* __restrict__ WhhL) {
    int stage, idx, U, u0; role_params(rw, stage, idx, U, u0);
    int wave = tid >> 6, lane = tid & 63;
    int ntl = slot >> 4, kt = slot & 15;
    int nt = 2*wave + ntl;
    if (stage == 0 && kt >= 8) return 0u;
    int gate = nt >> 2, usub = nt & 3;
    int j = gate*256 + u0 + usub*16 + (lane & 15);
    int khalf = lane >> 4;
    if (stage == 0) {
        int k = kt*32 + khalf*8 + 2*d;
        return pk(Whh0[(size_t)j*256 + k], Whh0[(size_t)j*256 + k + 1]);
    }
    if (kt < 8) {
        int k = kt*32 + khalf*8 + 2*d;
        const float* Wi = WihL + (size_t)(stage-1)*G4*258;
        return pk(Wi[(size_t)j*258 + 2 + k], Wi[(size_t)j*258 + 3 + k]);
    }
    int k = (kt-8)*32 + khalf*8 + 2*d;
    const float* Wh = WhhL + (size_t)(stage-1)*G4*256;
    return pk(Wh[(size_t)j*256 + k], Wh[(size_t)j*256 + k + 1]);
}

// ---------------- prep kernels ----------------
__global__ void pack_wreg(const float* __restrict__ Whh0, const float* __restrict__ WihL,
                          const float* __restrict__ WhhL, uint32_t* __restrict__ wsd) {
    int slot = blockIdx.x & 31, rw = blockIdx.x >> 5;   // grid 12*32
    int tid = threadIdx.x;
    uint32_t* dst = wsd + OFF_WREG + ((size_t)(rw*32 + slot)*512 + tid)*4;
    dst[0] = fetch_wdw(rw, tid, slot, 0, Whh0, WihL, WhhL);
    dst[1] = fetch_wdw(rw, tid, slot, 1, Whh0, WihL, WhhL);
    dst[2] = fetch_wdw(rw, tid, slot, 2, Whh0, WihL, WhhL);
    dst[3] = fetch_wdw(rw, tid, slot, 3, Whh0, WihL, WhhL);
}

__global__ void pack_misc(const float* __restrict__ Wih0,
                          const float* __restrict__ bih0, const float* __restrict__ bhh0,
                          const float* __restrict__ WihL,
                          const float* __restrict__ bihL, const float* __restrict__ bhhL,
                          uint32_t* __restrict__ wsd) {
    int id = blockIdx.x * blockDim.x + threadIdx.x;
    if (id >= NROLE*768) return;
    int rw = id / 768, i = id % 768;
    int qq = i / 256, rem = i % 256, gate = rem / 64, u = rem % 64;
    int stage, idx, U, u0; role_params(rw, stage, idx, U, u0);
    int j = gate*256 + u0 + u;
    float v;
    if (stage == 0)      v = (qq == 0) ? bih0[j] + bhh0[j] : Wih0[j*2 + (qq-1)];
    else if (stage == 1) v = (qq == 0) ? bihL[j] + bhhL[j] : WihL[(size_t)j*258 + (qq-1)];
    else                 v = (qq == 0) ? bihL[G4+j] + bhhL[G4+j]
                                       : WihL[(size_t)G4*258 + (size_t)j*258 + (qq-1)];
    ((float*)wsd)[OFF_MISC + id] = v;
}

__global__ void pack_head(const float* __restrict__ Wg, const float* __restrict__ bg,
                          const float* __restrict__ Ww, const float* __restrict__ bw,
                          uint32_t* __restrict__ wsd) {
    int id = blockIdx.x * blockDim.x + threadIdx.x;
    if (id < 120*132) {
        int jo = id / 132, d = id % 132;
        uint32_t v = 0;
        if (d < 128) {
            int k = 2*d;
            const float* row = (jo < 100) ? (Wg + (size_t)jo*258) : (Ww + (size_t)(jo-100)*258);
            v = pk(row[2+k], row[3+k]);
        }
        wsd[OFF_HEADW + id] = v;
    } else if (id < 120*132 + 360) {
        int p = id - 120*132, jo = p/3, qq = p%3;
        const float* row = (jo < 100) ? (Wg + (size_t)jo*258) : (Ww + (size_t)(jo-100)*258);
        float v = (qq == 0) ? ((jo < 100) ? bg[jo] : bw[jo-100]) : row[qq-1];
        ((float*)wsd)[OFF_HXB + p] = v;
    }
}

__global__ void zero_cnt(uint32_t* __restrict__ wsd) {
    int id = blockIdx.x * blockDim.x + threadIdx.x;
    if (id < NGROUPS*448) wsd[OFF_CNT + id] = 0;
}

// ---------------- sync primitives: PC counters ONLY ----------------
// Ack-free safety: head dependency bounds stage0 <= stage2+3; data deps bound
// stage1 <= stage0, stage2 <= stage1 -> pipeline spread <= 3 beats < ring-4.
// Verified slot-by-slot: no ring-4 slot is overwritten while a reader within
// the 3-beat window can still need it.
__device__ __forceinline__ void pollCnt(uint32_t* c, uint32_t tgt) {
    int spins = 0;
    while (__hip_atomic_load(c, __ATOMIC_RELAXED, __HIP_MEMORY_SCOPE_AGENT) < tgt) {
        __builtin_amdgcn_s_sleep(1);
        if (++spins > (1 << 24)) break;   // bailout: loud wrong answer beats a hang
    }
}
__device__ __forceinline__ void bump(uint32_t* c) {
    __hip_atomic_fetch_add(c, 1u, __ATOMIC_RELAXED, __HIP_MEMORY_SCOPE_AGENT);
}
#define PCC(L) (cnt + (L)*16)

// 8 MFMA k-steps over one 256-wide h operand (padded LDS rows of 132 dw)
template<int SO>
__device__ __forceinline__ void mfma8(f32x4v& ac0, f32x4v& ac1, const f16x8v (&wrf)[32],
                                      const uint32_t* hb, int rA, int khalf) {
#pragma unroll
    for (int kt = 0; kt < 8; ++kt) {
        uint4 hv = *(const uint4*)(hb + rA*132 + kt*16 + khalf*4);
        f16x8v a = __builtin_bit_cast(f16x8v, hv);
        ac0 = MFMA16(a, wrf[SO + kt], ac0);
        ac1 = MFMA16(a, wrf[16 + SO + kt], ac1);
    }
}

#define READH(BUF, L, SLOT)                                                        \
    { _Pragma("unroll")                                                            \
      for (int p_ = 0; p_ < 2; ++p_) {                                             \
        int idx_ = tid + p_*512;                                                   \
        int r_ = idx_ >> 6, i_ = idx_ & 63;                                        \
        uint64_t v_ = __hip_atomic_load(hbuf64 + (((L)*4 + (SLOT))*16 + r_)*64 + i_, \
                                        __ATOMIC_RELAXED, __HIP_MEMORY_SCOPE_AGENT); \
        *(uint64_t*)&h_lds[BUF][r_][2*i_] = v_;                                    \
      } }

#define DWRITE()                                                                   \
    { _Pragma("unroll")                                                            \
      for (int rg = 0; rg < 4; ++rg) g_s[m0 + rg][gate0][ul0] = ac0[rg];           \
      _Pragma("unroll")                                                            \
      for (int rg = 0; rg < 4; ++rg) g_s[m0 + rg][gate1][ul1] = ac1[rg]; }

#define UPDATE_PASS(PASS, CST, LYR, SLOT)                                          \
    { int r_ = tid & 15, u_ = (PASS)*32 + (tid >> 4);                              \
      float x0 = x_cur[r_][0], x1 = x_cur[r_][1];                                  \
      float gi = g_s[r_][0][u_] + misc_s[0][0][u_] + x0*misc_s[1][0][u_] + x1*misc_s[2][0][u_]; \
      float gf = g_s[r_][1][u_] + misc_s[0][1][u_] + x0*misc_s[1][1][u_] + x1*misc_s[2][1][u_]; \
      float gg = g_s[r_][2][u_] + misc_s[0][2][u_] + x0*misc_s[1][2][u_] + x1*misc_s[2][2][u_]; \
      float go = g_s[r_][3][u_] + misc_s[0][3][u_] + x0*misc_s[1][3][u_] + x1*misc_s[2][3][u_]; \
      float cc_ = sigf(gf)*(CST) + sigf(gi)*tanhfast(gg);                          \
      float hval = sigf(go)*tanhfast(cc_);  (CST) = cc_;                           \
      float h1_ = __shfl_down(hval, 16), h2_ = __shfl_down(hval, 32), h3_ = __shfl_down(hval, 48); \
      if ((tid & 63) < 16) {                                                       \
          uint64_t pv = (uint64_t)pk(hval, h1_) | ((uint64_t)pk(h2_, h3_) << 32);  \
          __hip_atomic_store(hbuf64 + (((LYR)*4 + (SLOT))*16 + r_)*64              \
                                 + (u0 >> 2) + (PASS)*8 + (tid >> 6), pv,          \
                             __ATOMIC_RELAXED, __HIP_MEMORY_SCOPE_AGENT);          \
      } }

#define HEAD_COMPUTE(TT, SLH)                                                      \
    { int jol = tid >> 4, rr2 = tid & 15;                                          \
      float acch = 0.0f;                                                           \
      if (jol < 30) {                                                              \
          _Pragma("unroll")                                                        \
          for (int d4 = 0; d4 < 32; ++d4) {                                        \
              uint4 wv = *(const uint4*)&headw_s[jol*132 + d4*4];                  \
              uint4 hv = *(const uint4*)&h_lds[1][rr2][d4*4];                      \
              acch = dot2f(wv.x, hv.x, acch); acch = dot2f(wv.y, hv.y, acch);      \
              acch = dot2f(wv.z, hv.z, acch); acch = dot2f(wv.w, hv.w, acch);      \
          }                                                                        \
          int jo = idx*30 + jol;                                                   \
          float xa = x_ring[SLH][rr2][0], xb = x_ring[SLH][rr2][1];                \
          acch += hxb_s[jol*3] + xa*hxb_s[jol*3+1] + xb*hxb_s[jol*3+2];            \
          if (jo < NOUT) out[((size_t)(b0 + rr2)*T_STEPS + (TT))*NOUT + jo] = acch; \
          else           wl_s[rr2][jo - NOUT] = acch;                              \
      }                                                                            \
      __syncthreads();                                                             \
      if (idx == 3 && tid < 16) {                                                  \
          int r = tid;                                                             \
          float mx = -1e30f;                                                       \
          _Pragma("unroll")                                                        \
          for (int m = 0; m < NW; ++m) mx = fmaxf(mx, wl_s[r][m]);                 \
          float ss = 0.0f, ee[NW];                                                 \
          _Pragma("unroll")                                                        \
          for (int m = 0; m < NW; ++m) { ee[m] = __expf(wl_s[r][m] - mx); ss += ee[m]; } \
          float inv = 1.0f / ss;                                                   \
          size_t bo = GOFF + ((size_t)(b0 + r)*T_STEPS + (TT))*NW;                 \
          _Pragma("unroll")                                                        \
          for (int m = 0; m < NW; ++m) out[bo + m] = ee[m]*inv;                    \
      } }

template <bool WSPACK>
__global__ __launch_bounds__(NTHM, 1)
void lstm_pipe(const float* __restrict__ x, uint32_t* __restrict__ wsd,
               float* __restrict__ out,
               const float* __restrict__ Whh0, const float* __restrict__ WihL,
               const float* __restrict__ WhhL) {
    __shared__ __align__(16) uint32_t h_lds[2][16][132];   // fp16-pair dw, padded stride
    __shared__ float    g_s[16][4][65];
    __shared__ float    misc_s[3][4][64];
    __shared__ float    x_cur[16][2];
    __shared__ float    x_ring[4][16][2];
    __shared__ __align__(16) uint32_t headw_s[30*132];
    __shared__ float    hxb_s[90];
    __shared__ float    wl_s[16][NW];

    const int tid = threadIdx.x;
    const int bid = blockIdx.x;
    const int g  = bid & (NGROUPS - 1);   // same g -> bids differ by 8 -> same XCD
    const int rw = bid >> 3;              // role 0..11
    int stage, idx, U, u0; role_params(rw, stage, idx, U, u0);
    const int b0 = g * BT;
    const int wave = tid >> 6, lane = tid & 63;
    const int rA = lane & 15, khalf = lane >> 4;
    const int m0 = khalf * 4;
    const int nt0 = 2*wave, nt1 = 2*wave + 1;
    const int gate0 = nt0 >> 2, ul0 = (nt0 & 3)*16 + rA;
    const int gate1 = nt1 >> 2, ul1 = (nt1 & 3)*16 + rA;

    uint64_t* hbuf64 = (uint64_t*)(wsd + OFF_HBUF) + (size_t)g * 12288;
    uint32_t* cnt = wsd + OFF_CNT + g * 448;
    const float* wsf = (const float*)wsd;

    // ---- persistent weights: B-fragments in VGPRs ----
    f16x8v wrf[32];
    if (WSPACK) {
#pragma unroll
        for (int s = 0; s < 32; ++s) {
            uint4 v = *(const uint4*)(wsd + OFF_WREG + ((size_t)(rw*32 + s)*512 + tid)*4);
            wrf[s] = __builtin_bit_cast(f16x8v, v);
        }
    } else {
#pragma unroll
        for (int s = 0; s < 32; ++s) {
            uint4 v;
            v.x = fetch_wdw(rw, tid, s, 0, Whh0, WihL, WhhL);
            v.y = fetch_wdw(rw, tid, s, 1, Whh0, WihL, WhhL);
            v.z = fetch_wdw(rw, tid, s, 2, Whh0, WihL, WhhL);
            v.w = fetch_wdw(rw, tid, s, 3, Whh0, WihL, WhhL);
            wrf[s] = __builtin_bit_cast(f16x8v, v);
        }
    }

    // ---- init LDS ----
    for (int i = tid; i < 2*16*132; i += NTHM) (&h_lds[0][0][0])[i] = 0u;
    for (int i = tid; i < 768;      i += NTHM) (&misc_s[0][0][0])[i] = wsf[OFF_MISC + rw*768 + i];
    if (stage == 0) {
        for (int i = tid; i < 30*132; i += NTHM) headw_s[i] = wsd[OFF_HEADW + idx*30*132 + i];
        for (int i = tid; i < 90;     i += NTHM) hxb_s[i]   = wsf[OFF_HXB + idx*90 + i];
    }
    float c_st0 = 0.0f, c_st1 = 0.0f;
    __syncthreads();

    const f32x4v zf4 = {0.0f, 0.0f, 0.0f, 0.0f};

    if (stage == 0) {
        // ===== stage0: L0 publishes first; head (t-3) strictly after the post =====
        for (int t = 0; t <= 1002; ++t) {
            const bool doL0 = (t < T_STEPS);
            const bool doHd = (t >= 3);
            const int th = t - 3;
            const int sl = t & 3, slp = (t - 1) & 3, slh = th & 3;
            float xv = 0.0f;
            if (doL0 && tid < 32)
                xv = x[((size_t)(b0 + (tid >> 1))*T_STEPS + t)*2 + (tid & 1)];
            if (tid == 0 && doL0 && t >= 1) pollCnt(PCC(0), 4u*(uint32_t)t);
            __syncthreads();
            if (doL0 && t >= 1) READH(0, 0, slp)        // h0@(t-1)
            if (doL0 && tid < 32) {
                x_cur[tid >> 1][tid & 1] = xv;
                x_ring[sl][tid >> 1][tid & 1] = xv;
            }
            __syncthreads();
            if (doL0) {
                f32x4v ac0 = zf4, ac1 = zf4;
                mfma8<0>(ac0, ac1, wrf, &h_lds[0][0][0], rA, khalf);
                DWRITE()
            }
            __syncthreads();
            if (doL0) {
                UPDATE_PASS(0, c_st0, 0, sl)
                UPDATE_PASS(1, c_st1, 0, sl)
            }
            __syncthreads();
            if (tid == 0 && doL0) bump(PCC(0));         // h0@t published
            // ---- head phase (off the publish path; bounds stage0 lead <= 3) ----
            if (doHd) {
                if (tid == 0) pollCnt(PCC(2), 4u*(uint32_t)(t - 2));
                __syncthreads();
                READH(1, 2, slh)                        // h2@(t-3)
                __syncthreads();
                HEAD_COMPUTE(th, slh)
            }
        }
    } else {
        // ===== stage1 / stage2: fused dual-read, minimal protocol =====
        const int OWN_L = stage, IN_L = stage - 1;
        for (int t = 0; t < T_STEPS; ++t) {
            const int sl = t & 3, slp = (t - 1) & 3;
            float xv = 0.0f;
            if (tid < 32)
                xv = x[((size_t)(b0 + (tid >> 1))*T_STEPS + t)*2 + (tid & 1)];
            if (tid == 0) {
                if (t >= 1) pollCnt(PCC(OWN_L), 4u*(uint32_t)t);       // own h@t-1
                pollCnt(PCC(IN_L), 4u*(uint32_t)(t + 1));              // skip input h@t
            }
            __syncthreads();
            READH(0, IN_L, sl)                                         // both reads issued
            if (t >= 1) READH(1, OWN_L, slp)                           //   back-to-back
            if (tid < 32) x_cur[tid >> 1][tid & 1] = xv;
            __syncthreads();
            f32x4v ac0 = zf4, ac1 = zf4;
            mfma8<0>(ac0, ac1, wrf, &h_lds[0][0][0], rA, khalf);       // skip matrix
            mfma8<8>(ac0, ac1, wrf, &h_lds[1][0][0], rA, khalf);       // recurrent matrix
            DWRITE()
            __syncthreads();
            UPDATE_PASS(0, c_st0, OWN_L, sl)
            UPDATE_PASS(1, c_st1, OWN_L, sl)
            __syncthreads();
            if (tid == 0) bump(PCC(OWN_L));
        }
    }
}

extern "C" void kernel_launch(void* const* d_in, const int* in_sizes, int n_in,
                              void* d_out, int out_size, void* d_ws, size_t ws_size,
                              hipStream_t stream) {
    const float* x    = (const float*)d_in[0];
    const float* Wih0 = (const float*)d_in[1];
    const float* Whh0 = (const float*)d_in[2];
    const float* bih0 = (const float*)d_in[3];
    const float* bhh0 = (const float*)d_in[4];
    const float* WihL = (const float*)d_in[5];
    const float* WhhL = (const float*)d_in[6];
    const float* bihL = (const float*)d_in[7];
    const float* bhhL = (const float*)d_in[8];
    const float* Wg   = (const float*)d_in[9];
    const float* bg   = (const float*)d_in[10];
    const float* Ww   = (const float*)d_in[11];
    const float* bw   = (const float*)d_in[12];
    float*    out = (float*)d_out;
    uint32_t* wsd = (uint32_t*)d_ws;
    (void)in_sizes; (void)n_in; (void)out_size;

    const bool wspack = ws_size >= WS_DW * 4;

    zero_cnt<<<14, 256, 0, stream>>>(wsd);
    pack_misc<<<36, 256, 0, stream>>>(Wih0, bih0, bhh0, WihL, bihL, bhhL, wsd);
    pack_head<<<64, 256, 0, stream>>>(Wg, bg, Ww, bw, wsd);
    if (wspack)
        pack_wreg<<<NROLE*32, 512, 0, stream>>>(Whh0, WihL, WhhL, wsd);

    dim3 grid(NGROUPS * NROLE), block(NTHM);
    void* args[] = {(void*)&x, (void*)&wsd, (void*)&out,
                    (void*)&Whh0, (void*)&WihL, (void*)&WhhL};
    if (wspack) {
        hipError_t err = hipLaunchCooperativeKernel((const void*)lstm_pipe<true>,
                                                    grid, block, args, 0, stream);
        if (err != hipSuccess)
            lstm_pipe<true><<<grid, block, 0, stream>>>(x, wsd, out, Whh0, WihL, WhhL);
    } else {
        hipError_t err = hipLaunchCooperativeKernel((const void*)lstm_pipe<false>,
                                                    grid, block, args, 0, stream);
        if (err != hipSuccess)
            lstm_pipe<false><<<grid, block, 0, stream>>>(x, wsd, out, Whh0, WihL, WhhL);
    }
}

// Round 16
// 3866.927 us; speedup vs baseline: 7.2382x; 1.0238x over previous
//
#include <hip/hip_runtime.h>
#include <hip/hip_fp16.h>
#include <stdint.h>

// ---------------- problem constants ----------------
#define T_STEPS 1000
#define G4      1024
#define NOUT    100
#define NW      20
#define NTHM    512
#define NGROUPS 8       // batch groups of 16 rows
#define NROLE   12      // 0-3 stage0(L0+head), 4-7 stage1, 8-11 stage2; U=64 each
#define BT      16
#define NSLOT   8       // hbuf ring slots (was 4)
#define HLAG    5       // head lag (was 3) -> feedback slack 5 beats

// ---------------- ws layout (dword offsets) ----------------
// hbuf: [8 groups][3 layers][8 slots][16 rows][64 u64]
constexpr int    OFF_HBUF  = 0;
constexpr int    OFF_CNT   = OFF_HBUF + NGROUPS*3*NSLOT*16*128;  // 393216: [8][448] (3 PCs used)
constexpr int    OFF_HEADW = OFF_CNT + NGROUPS*448;              // 396800: [120][132]
constexpr int    OFF_HXB   = OFF_HEADW + 120*132;                // 412640: [120][3] f32
constexpr int    OFF_MISC  = OFF_HXB + 360;                      // 413000: [12 roles][3][4][64] f32
constexpr int    OFF_WREG  = OFF_MISC + NROLE*768;               // 422216: [12][32][512][4dw]
constexpr size_t WS_DW     = (size_t)OFF_WREG + (size_t)NROLE*32*512*4;  // ~4.83 MB
constexpr size_t GOFF      = (size_t)128*1000*100;

__device__ __forceinline__ float sigf(float x)     { return 1.0f / (1.0f + __expf(-x)); }
__device__ __forceinline__ float tanhfast(float x) { return 2.0f / (1.0f + __expf(-2.0f * x)) - 1.0f; }

typedef _Float16 h2v    __attribute__((ext_vector_type(2)));
typedef _Float16 f16x8v __attribute__((ext_vector_type(8)));
typedef float    f32x4v __attribute__((ext_vector_type(4)));
#define MFMA16(A, B, C) __builtin_amdgcn_mfma_f32_16x16x32_f16((A), (B), (C), 0, 0, 0)

__device__ __forceinline__ float dot2f(uint32_t w, uint32_t h, float acc) {
    return __builtin_amdgcn_fdot2(__builtin_bit_cast(h2v, w),
                                  __builtin_bit_cast(h2v, h), acc, false);
}
__device__ __forceinline__ uint32_t pk(float a, float b) {
    __half2 h = __floats2half2_rn(a, b);
    return *reinterpret_cast<uint32_t*>(&h);
}

__device__ __forceinline__ void role_params(int rw, int& stage, int& idx, int& U, int& u0) {
    stage = rw >> 2; idx = rw & 3; U = 64; u0 = 64*idx;
}

// B-fragment weight dword (role rw, thread tid, slot = ntl*16+kt, dword d).
// wave=tid>>6, lane=tid&63; nt = 2*wave+ntl (NT=16).
// j = gate*256 + u0 + usub*16 + (lane&15); k = [kt or kt-8]*32 + (lane>>4)*8 + 2d.
// kt<8: stage0 Whh0 / stage1,2 skip Wih; kt>=8: recur Whh (stage0 unused -> 0).
__device__ __forceinline__ uint32_t fetch_wdw(int rw, int tid, int slot, int d,
                                              const float* __restrict__ Whh0,
                                              const float* __restrict__ WihL,
                                              const float* __restrict__ WhhL) {
    int stage, idx, U, u0; role_params(rw, stage, idx, U, u0);
    int wave = tid >> 6, lane = tid & 63;
    int ntl = slot >> 4, kt = slot & 15;
    int nt = 2*wave + ntl;
    if (stage == 0 && kt >= 8) return 0u;
    int gate = nt >> 2, usub = nt & 3;
    int j = gate*256 + u0 + usub*16 + (lane & 15);
    int khalf = lane >> 4;
    if (stage == 0) {
        int k = kt*32 + khalf*8 + 2*d;
        return pk(Whh0[(size_t)j*256 + k], Whh0[(size_t)j*256 + k + 1]);
    }
    if (kt < 8) {
        int k = kt*32 + khalf*8 + 2*d;
        const float* Wi = WihL + (size_t)(stage-1)*G4*258;
        return pk(Wi[(size_t)j*258 + 2 + k], Wi[(size_t)j*258 + 3 + k]);
    }
    int k = (kt-8)*32 + khalf*8 + 2*d;
    const float* Wh = WhhL + (size_t)(stage-1)*G4*256;
    return pk(Wh[(size_t)j*256 + k], Wh[(size_t)j*256 + k + 1]);
}

// ---------------- prep kernels ----------------
__global__ void pack_wreg(const float* __restrict__ Whh0, const float* __restrict__ WihL,
                          const float* __restrict__ WhhL, uint32_t* __restrict__ wsd) {
    int slot = blockIdx.x & 31, rw = blockIdx.x >> 5;   // grid 12*32
    int tid = threadIdx.x;
    uint32_t* dst = wsd + OFF_WREG + ((size_t)(rw*32 + slot)*512 + tid)*4;
    dst[0] = fetch_wdw(rw, tid, slot, 0, Whh0, WihL, WhhL);
    dst[1] = fetch_wdw(rw, tid, slot, 1, Whh0, WihL, WhhL);
    dst[2] = fetch_wdw(rw, tid, slot, 2, Whh0, WihL, WhhL);
    dst[3] = fetch_wdw(rw, tid, slot, 3, Whh0, WihL, WhhL);
}

__global__ void pack_misc(const float* __restrict__ Wih0,
                          const float* __restrict__ bih0, const float* __restrict__ bhh0,
                          const float* __restrict__ WihL,
                          const float* __restrict__ bihL, const float* __restrict__ bhhL,
                          uint32_t* __restrict__ wsd) {
    int id = blockIdx.x * blockDim.x + threadIdx.x;
    if (id >= NROLE*768) return;
    int rw = id / 768, i = id % 768;
    int qq = i / 256, rem = i % 256, gate = rem / 64, u = rem % 64;
    int stage, idx, U, u0; role_params(rw, stage, idx, U, u0);
    int j = gate*256 + u0 + u;
    float v;
    if (stage == 0)      v = (qq == 0) ? bih0[j] + bhh0[j] : Wih0[j*2 + (qq-1)];
    else if (stage == 1) v = (qq == 0) ? bihL[j] + bhhL[j] : WihL[(size_t)j*258 + (qq-1)];
    else                 v = (qq == 0) ? bihL[G4+j] + bhhL[G4+j]
                                       : WihL[(size_t)G4*258 + (size_t)j*258 + (qq-1)];
    ((float*)wsd)[OFF_MISC + id] = v;
}

__global__ void pack_head(const float* __restrict__ Wg, const float* __restrict__ bg,
                          const float* __restrict__ Ww, const float* __restrict__ bw,
                          uint32_t* __restrict__ wsd) {
    int id = blockIdx.x * blockDim.x + threadIdx.x;
    if (id < 120*132) {
        int jo = id / 132, d = id % 132;
        uint32_t v = 0;
        if (d < 128) {
            int k = 2*d;
            const float* row = (jo < 100) ? (Wg + (size_t)jo*258) : (Ww + (size_t)(jo-100)*258);
            v = pk(row[2+k], row[3+k]);
        }
        wsd[OFF_HEADW + id] = v;
    } else if (id < 120*132 + 360) {
        int p = id - 120*132, jo = p/3, qq = p%3;
        const float* row = (jo < 100) ? (Wg + (size_t)jo*258) : (Ww + (size_t)(jo-100)*258);
        float v = (qq == 0) ? ((jo < 100) ? bg[jo] : bw[jo-100]) : row[qq-1];
        ((float*)wsd)[OFF_HXB + p] = v;
    }
}

__global__ void zero_cnt(uint32_t* __restrict__ wsd) {
    int id = blockIdx.x * blockDim.x + threadIdx.x;
    if (id < NGROUPS*448) wsd[OFF_CNT + id] = 0;
}

// ---------------- sync primitives: PC counters ONLY ----------------
// Ack-free safety (ring-8, HLAG=5): head dependency bounds stage0 <= stage2 +
// HLAG+1 = 6; data deps bound stage1 <= stage0, stage2 <= stage1 -> pipeline
// spread <= 6 < 8 slots (2-slot margin). Verified per layer buffer, incl. the
// stage2-overwrite vs stage0-head-read case via the data-dependency chain
// (stage2@t+8 requires stage0@t+8 > t+HLAG, so head@t already executed).
__device__ __forceinline__ void pollCnt(uint32_t* c, uint32_t tgt) {
    int spins = 0;
    while (__hip_atomic_load(c, __ATOMIC_RELAXED, __HIP_MEMORY_SCOPE_AGENT) < tgt) {
        __builtin_amdgcn_s_sleep(1);
        if (++spins > (1 << 24)) break;   // bailout: loud wrong answer beats a hang
    }
}
__device__ __forceinline__ void bump(uint32_t* c) {
    __hip_atomic_fetch_add(c, 1u, __ATOMIC_RELAXED, __HIP_MEMORY_SCOPE_AGENT);
}
#define PCC(L) (cnt + (L)*16)

// 8 MFMA k-steps over one 256-wide h operand (padded LDS rows of 132 dw)
template<int SO>
__device__ __forceinline__ void mfma8(f32x4v& ac0, f32x4v& ac1, const f16x8v (&wrf)[32],
                                      const uint32_t* hb, int rA, int khalf) {
#pragma unroll
    for (int kt = 0; kt < 8; ++kt) {
        uint4 hv = *(const uint4*)(hb + rA*132 + kt*16 + khalf*4);
        f16x8v a = __builtin_bit_cast(f16x8v, hv);
        ac0 = MFMA16(a, wrf[SO + kt], ac0);
        ac1 = MFMA16(a, wrf[16 + SO + kt], ac1);
    }
}

#define READH(BUF, L, SLOT)                                                        \
    { _Pragma("unroll")                                                            \
      for (int p_ = 0; p_ < 2; ++p_) {                                             \
        int idx_ = tid + p_*512;                                                   \
        int r_ = idx_ >> 6, i_ = idx_ & 63;                                        \
        uint64_t v_ = __hip_atomic_load(hbuf64 + (((L)*NSLOT + (SLOT))*16 + r_)*64 + i_, \
                                        __ATOMIC_RELAXED, __HIP_MEMORY_SCOPE_AGENT); \
        *(uint64_t*)&h_lds[BUF][r_][2*i_] = v_;                                    \
      } }

#define DWRITE()                                                                   \
    { _Pragma("unroll")                                                            \
      for (int rg = 0; rg < 4; ++rg) g_s[m0 + rg][gate0][ul0] = ac0[rg];           \
      _Pragma("unroll")                                                            \
      for (int rg = 0; rg < 4; ++rg) g_s[m0 + rg][gate1][ul1] = ac1[rg]; }

#define UPDATE_PASS(PASS, CST, LYR, SLOT)                                          \
    { int r_ = tid & 15, u_ = (PASS)*32 + (tid >> 4);                              \
      float x0 = x_cur[r_][0], x1 = x_cur[r_][1];                                  \
      float gi = g_s[r_][0][u_] + misc_s[0][0][u_] + x0*misc_s[1][0][u_] + x1*misc_s[2][0][u_]; \
      float gf = g_s[r_][1][u_] + misc_s[0][1][u_] + x0*misc_s[1][1][u_] + x1*misc_s[2][1][u_]; \
      float gg = g_s[r_][2][u_] + misc_s[0][2][u_] + x0*misc_s[1][2][u_] + x1*misc_s[2][2][u_]; \
      float go = g_s[r_][3][u_] + misc_s[0][3][u_] + x0*misc_s[1][3][u_] + x1*misc_s[2][3][u_]; \
      float cc_ = sigf(gf)*(CST) + sigf(gi)*tanhfast(gg);                          \
      float hval = sigf(go)*tanhfast(cc_);  (CST) = cc_;                           \
      float h1_ = __shfl_down(hval, 16), h2_ = __shfl_down(hval, 32), h3_ = __shfl_down(hval, 48); \
      if ((tid & 63) < 16) {                                                       \
          uint64_t pv = (uint64_t)pk(hval, h1_) | ((uint64_t)pk(h2_, h3_) << 32);  \
          __hip_atomic_store(hbuf64 + (((LYR)*NSLOT + (SLOT))*16 + r_)*64          \
                                 + (u0 >> 2) + (PASS)*8 + (tid >> 6), pv,          \
                             __ATOMIC_RELAXED, __HIP_MEMORY_SCOPE_AGENT);          \
      } }

#define HEAD_COMPUTE(TT, SLH)                                                      \
    { int jol = tid >> 4, rr2 = tid & 15;                                          \
      float acch = 0.0f;                                                           \
      if (jol < 30) {                                                              \
          _Pragma("unroll")                                                        \
          for (int d4 = 0; d4 < 32; ++d4) {                                        \
              uint4 wv = *(const uint4*)&headw_s[jol*132 + d4*4];                  \
              uint4 hv = *(const uint4*)&h_lds[1][rr2][d4*4];                      \
              acch = dot2f(wv.x, hv.x, acch); acch = dot2f(wv.y, hv.y, acch);      \
              acch = dot2f(wv.z, hv.z, acch); acch = dot2f(wv.w, hv.w, acch);      \
          }                                                                        \
          int jo = idx*30 + jol;                                                   \
          float xa = x_ring[SLH][rr2][0], xb = x_ring[SLH][rr2][1];                \
          acch += hxb_s[jol*3] + xa*hxb_s[jol*3+1] + xb*hxb_s[jol*3+2];            \
          if (jo < NOUT) out[((size_t)(b0 + rr2)*T_STEPS + (TT))*NOUT + jo] = acch; \
          else           wl_s[rr2][jo - NOUT] = acch;                              \
      }                                                                            \
      __syncthreads();                                                             \
      if (idx == 3 && tid < 16) {                                                  \
          int r = tid;                                                             \
          float mx = -1e30f;                                                       \
          _Pragma("unroll")                                                        \
          for (int m = 0; m < NW; ++m) mx = fmaxf(mx, wl_s[r][m]);                 \
          float ss = 0.0f, ee[NW];                                                 \
          _Pragma("unroll")                                                        \
          for (int m = 0; m < NW; ++m) { ee[m] = __expf(wl_s[r][m] - mx); ss += ee[m]; } \
          float inv = 1.0f / ss;                                                   \
          size_t bo = GOFF + ((size_t)(b0 + r)*T_STEPS + (TT))*NW;                 \
          _Pragma("unroll")                                                        \
          for (int m = 0; m < NW; ++m) out[bo + m] = ee[m]*inv;                    \
      } }

template <bool WSPACK>
__global__ __launch_bounds__(NTHM, 1)
void lstm_pipe(const float* __restrict__ x, uint32_t* __restrict__ wsd,
               float* __restrict__ out,
               const float* __restrict__ Whh0, const float* __restrict__ WihL,
               const float* __restrict__ WhhL) {
    __shared__ __align__(16) uint32_t h_lds[2][16][132];   // fp16-pair dw, padded stride
    __shared__ float    g_s[16][4][65];
    __shared__ float    misc_s[3][4][64];
    __shared__ float    x_cur[16][2];
    __shared__ float    x_ring[NSLOT][16][2];
    __shared__ __align__(16) uint32_t headw_s[30*132];
    __shared__ float    hxb_s[90];
    __shared__ float    wl_s[16][NW];

    const int tid = threadIdx.x;
    const int bid = blockIdx.x;
    const int g  = bid & (NGROUPS - 1);   // same g -> bids differ by 8 -> same XCD
    const int rw = bid >> 3;              // role 0..11
    int stage, idx, U, u0; role_params(rw, stage, idx, U, u0);
    const int b0 = g * BT;
    const int wave = tid >> 6, lane = tid & 63;
    const int rA = lane & 15, khalf = lane >> 4;
    const int m0 = khalf * 4;
    const int nt0 = 2*wave, nt1 = 2*wave + 1;
    const int gate0 = nt0 >> 2, ul0 = (nt0 & 3)*16 + rA;
    const int gate1 = nt1 >> 2, ul1 = (nt1 & 3)*16 + rA;

    uint64_t* hbuf64 = (uint64_t*)(wsd + OFF_HBUF) + (size_t)g * (3*NSLOT*16*64);
    uint32_t* cnt = wsd + OFF_CNT + g * 448;
    const float* wsf = (const float*)wsd;

    // ---- persistent weights: B-fragments in VGPRs ----
    f16x8v wrf[32];
    if (WSPACK) {
#pragma unroll
        for (int s = 0; s < 32; ++s) {
            uint4 v = *(const uint4*)(wsd + OFF_WREG + ((size_t)(rw*32 + s)*512 + tid)*4);
            wrf[s] = __builtin_bit_cast(f16x8v, v);
        }
    } else {
#pragma unroll
        for (int s = 0; s < 32; ++s) {
            uint4 v;
            v.x = fetch_wdw(rw, tid, s, 0, Whh0, WihL, WhhL);
            v.y = fetch_wdw(rw, tid, s, 1, Whh0, WihL, WhhL);
            v.z = fetch_wdw(rw, tid, s, 2, Whh0, WihL, WhhL);
            v.w = fetch_wdw(rw, tid, s, 3, Whh0, WihL, WhhL);
            wrf[s] = __builtin_bit_cast(f16x8v, v);
        }
    }

    // ---- init LDS ----
    for (int i = tid; i < 2*16*132; i += NTHM) (&h_lds[0][0][0])[i] = 0u;
    for (int i = tid; i < 768;      i += NTHM) (&misc_s[0][0][0])[i] = wsf[OFF_MISC + rw*768 + i];
    if (stage == 0) {
        for (int i = tid; i < 30*132; i += NTHM) headw_s[i] = wsd[OFF_HEADW + idx*30*132 + i];
        for (int i = tid; i < 90;     i += NTHM) hxb_s[i]   = wsf[OFF_HXB + idx*90 + i];
    }
    float c_st0 = 0.0f, c_st1 = 0.0f;
    __syncthreads();

    const f32x4v zf4 = {0.0f, 0.0f, 0.0f, 0.0f};

    if (stage == 0) {
        // ===== stage0: L0 publishes first; head (t-HLAG) strictly after the post =====
        for (int t = 0; t <= T_STEPS - 1 + HLAG; ++t) {
            const bool doL0 = (t < T_STEPS);
            const bool doHd = (t >= HLAG);
            const int th = t - HLAG;
            const int sl = t & (NSLOT-1), slp = (t - 1) & (NSLOT-1), slh = th & (NSLOT-1);
            float xv = 0.0f;
            if (doL0 && tid < 32)
                xv = x[((size_t)(b0 + (tid >> 1))*T_STEPS + t)*2 + (tid & 1)];
            if (tid == 0 && doL0 && t >= 1) pollCnt(PCC(0), 4u*(uint32_t)t);
            __syncthreads();
            if (doL0 && t >= 1) READH(0, 0, slp)        // h0@(t-1)
            if (doL0 && tid < 32) {
                x_cur[tid >> 1][tid & 1] = xv;
                x_ring[sl][tid >> 1][tid & 1] = xv;
            }
            __syncthreads();
            if (doL0) {
                f32x4v ac0 = zf4, ac1 = zf4;
                mfma8<0>(ac0, ac1, wrf, &h_lds[0][0][0], rA, khalf);
                DWRITE()
            }
            __syncthreads();
            if (doL0) {
                UPDATE_PASS(0, c_st0, 0, sl)
                UPDATE_PASS(1, c_st1, 0, sl)
            }
            __syncthreads();
            if (tid == 0 && doL0) bump(PCC(0));         // h0@t published
            // ---- head phase (off the publish path; bounds stage0 lead <= HLAG+1) ----
            if (doHd) {
                if (tid == 0) pollCnt(PCC(2), 4u*(uint32_t)(th + 1));
                __syncthreads();
                READH(1, 2, slh)                        // h2@(t-HLAG)
                __syncthreads();
                HEAD_COMPUTE(th, slh)
            }
        }
    } else {
        // ===== stage1 / stage2: fused dual-read, minimal protocol =====
        const int OWN_L = stage, IN_L = stage - 1;
        for (int t = 0; t < T_STEPS; ++t) {
            const int sl = t & (NSLOT-1), slp = (t - 1) & (NSLOT-1);
            float xv = 0.0f;
            if (tid < 32)
                xv = x[((size_t)(b0 + (tid >> 1))*T_STEPS + t)*2 + (tid & 1)];
            if (tid == 0) {
                if (t >= 1) pollCnt(PCC(OWN_L), 4u*(uint32_t)t);       // own h@t-1
                pollCnt(PCC(IN_L), 4u*(uint32_t)(t + 1));              // skip input h@t
            }
            __syncthreads();
            READH(0, IN_L, sl)                                         // both reads issued
            if (t >= 1) READH(1, OWN_L, slp)                           //   back-to-back
            if (tid < 32) x_cur[tid >> 1][tid & 1] = xv;
            __syncthreads();
            f32x4v ac0 = zf4, ac1 = zf4;
            mfma8<0>(ac0, ac1, wrf, &h_lds[0][0][0], rA, khalf);       // skip matrix
            mfma8<8>(ac0, ac1, wrf, &h_lds[1][0][0], rA, khalf);       // recurrent matrix
            DWRITE()
            __syncthreads();
            UPDATE_PASS(0, c_st0, OWN_L, sl)
            UPDATE_PASS(1, c_st1, OWN_L, sl)
            __syncthreads();
            if (tid == 0) bump(PCC(OWN_L));
        }
    }
}

extern "C" void kernel_launch(void* const* d_in, const int* in_sizes, int n_in,
                              void* d_out, int out_size, void* d_ws, size_t ws_size,
                              hipStream_t stream) {
    const float* x    = (const float*)d_in[0];
    const float* Wih0 = (const float*)d_in[1];
    const float* Whh0 = (const float*)d_in[2];
    const float* bih0 = (const float*)d_in[3];
    const float* bhh0 = (const float*)d_in[4];
    const float* WihL = (const float*)d_in[5];
    const float* WhhL = (const float*)d_in[6];
    const float* bihL = (const float*)d_in[7];
    const float* bhhL = (const float*)d_in[8];
    const float* Wg   = (const float*)d_in[9];
    const float* bg   = (const float*)d_in[10];
    const float* Ww   = (const float*)d_in[11];
    const float* bw   = (const float*)d_in[12];
    float*    out = (float*)d_out;
    uint32_t* wsd = (uint32_t*)d_ws;
    (void)in_sizes; (void)n_in; (void)out_size;

    const bool wspack = ws_size >= WS_DW * 4;

    zero_cnt<<<14, 256, 0, stream>>>(wsd);
    pack_misc<<<36, 256, 0, stream>>>(Wih0, bih0, bhh0, WihL, bihL, bhhL, wsd);
    pack_head<<<64, 256, 0, stream>>>(Wg, bg, Ww, bw, wsd);
    if (wspack)
        pack_wreg<<<NROLE*32, 512, 0, stream>>>(Whh0, WihL, WhhL, wsd);

    dim3 grid(NGROUPS * NROLE), block(NTHM);
    void* args[] = {(void*)&x, (void*)&wsd, (void*)&out,
                    (void*)&Whh0, (void*)&WihL, (void*)&WhhL};
    if (wspack) {
        hipError_t err = hipLaunchCooperativeKernel((const void*)lstm_pipe<true>,
                                                    grid, block, args, 0, stream);
        if (err != hipSuccess)
            lstm_pipe<true><<<grid, block, 0, stream>>>(x, wsd, out, Whh0, WihL, WhhL);
    } else {
        hipError_t err = hipLaunchCooperativeKernel((const void*)lstm_pipe<false>,
                                                    grid, block, args, 0, stream);
        if (err != hipSuccess)
            lstm_pipe<false><<<grid, block, 0, stream>>>(x, wsd, out, Whh0, WihL, WhhL);
    }
}